// Round 1
// baseline (1839.386 us; speedup 1.0000x reference)
//
#include <hip/hip_runtime.h>

typedef __bf16 bf16x4 __attribute__((ext_vector_type(4)));
typedef __bf16 bf16x8 __attribute__((ext_vector_type(8)));
typedef float f32x4 __attribute__((ext_vector_type(4)));
typedef int int4v __attribute__((ext_vector_type(4)));

#define LOG2E 1.44269504088896340736f

// ---------------------------------------------------------------- converts

__global__ void cvt_f32_bf16(const float* __restrict__ src, __bf16* __restrict__ dst, int n4)
{
    int i = blockIdx.x * blockDim.x + threadIdx.x;
    if (i >= n4) return;
    f32x4 v = *reinterpret_cast<const f32x4*>(src + (size_t)i * 4);
    bf16x4 o;
    #pragma unroll
    for (int k = 0; k < 4; ++k) o[k] = (__bf16)v[k];
    *reinterpret_cast<bf16x4*>(dst + (size_t)i * 4) = o;
}

// src (nmat, R, C) -> dst (nmat, C, R), bf16
__global__ void transpose_cvt(const float* __restrict__ src, __bf16* __restrict__ dst, int R, int C)
{
    int m = blockIdx.y;
    int n = R * C;
    int i = blockIdx.x * 256 + threadIdx.x;
    if (i >= n) return;
    int c = i / R, r = i - c * R;
    dst[(size_t)m * n + i] = (__bf16)src[(size_t)m * n + (size_t)r * C + c];
}

// src (nmat, R, C) -> dst (nmat, C, R), f32
__global__ void transpose_f32(const float* __restrict__ src, float* __restrict__ dst, int R, int C)
{
    int m = blockIdx.y;
    int n = R * C;
    int i = blockIdx.x * 256 + threadIdx.x;
    if (i >= n) return;
    int c = i / R, r = i - c * R;
    dst[(size_t)m * n + i] = src[(size_t)m * n + (size_t)r * C + c];
}

// ---------------------------------------------------------------- GEMM
// C[z][m][n] = sum_k A[z][m][k] * B[g][n][k] + bias[g][n]   (B^T layout)
// A: (M,K) row-major bf16; B: (N,K) row-major bf16; out f32 (Cf) or bf16 (Cb).
__global__ __launch_bounds__(256, 2)
void gemm_bt(const __bf16* __restrict__ A, size_t strideA,
             const __bf16* __restrict__ B, size_t strideB,
             const float* __restrict__ bias, int strideBias,
             float* Cf, __bf16* Cb, size_t strideC,
             const int* __restrict__ gidx,
             int K, int ldc, int relu)
{
    __shared__ __bf16 lA[128 * 32];
    __shared__ __bf16 lB[128 * 32];

    const int z = blockIdx.z;
    const int g = gidx ? gidx[z] : 0;
    const __bf16* Ab = A + (size_t)z * strideA;
    const __bf16* Bb = B + (size_t)g * strideB;
    const int bm = blockIdx.y * 128, bn = blockIdx.x * 128;
    const int t = threadIdx.x;
    const int w = t >> 6, lane = t & 63;
    const int wr = (w >> 1) * 64, wc = (w & 1) * 64;
    const int l16 = lane & 15, lk = lane >> 4;

    f32x4 acc[4][4] = {};

    for (int kt = 0; kt < K; kt += 32) {
        __syncthreads();
        #pragma unroll
        for (int r = 0; r < 2; ++r) {
            int c = t + r * 256;
            int row = c >> 2, kc = c & 3;
            *reinterpret_cast<int4v*>(&lA[row * 32 + kc * 8]) =
                *reinterpret_cast<const int4v*>(Ab + (size_t)(bm + row) * K + kt + kc * 8);
            *reinterpret_cast<int4v*>(&lB[row * 32 + kc * 8]) =
                *reinterpret_cast<const int4v*>(Bb + (size_t)(bn + row) * K + kt + kc * 8);
        }
        __syncthreads();
        bf16x8 af[4], bfr[4];
        #pragma unroll
        for (int i = 0; i < 4; ++i) {
            af[i]  = *reinterpret_cast<const bf16x8*>(&lA[(wr + i * 16 + l16) * 32 + lk * 8]);
            bfr[i] = *reinterpret_cast<const bf16x8*>(&lB[(wc + i * 16 + l16) * 32 + lk * 8]);
        }
        #pragma unroll
        for (int mi = 0; mi < 4; ++mi)
            #pragma unroll
            for (int ni = 0; ni < 4; ++ni)
                acc[mi][ni] = __builtin_amdgcn_mfma_f32_16x16x32_bf16(af[mi], bfr[ni], acc[mi][ni], 0, 0, 0);
    }

    const float* biasb = bias ? bias + (size_t)g * strideBias : nullptr;
    #pragma unroll
    for (int ni = 0; ni < 4; ++ni) {
        int col = bn + wc + ni * 16 + l16;
        float bv = biasb ? biasb[col] : 0.f;
        #pragma unroll
        for (int mi = 0; mi < 4; ++mi) {
            #pragma unroll
            for (int j = 0; j < 4; ++j) {
                int row = bm + wr + mi * 16 + lk * 4 + j;
                float v = acc[mi][ni][j] + bv;
                if (relu) v = fmaxf(v, 0.f);
                size_t o = (size_t)z * strideC + (size_t)row * ldc + col;
                if (Cf) Cf[o] = v;
                else    Cb[o] = (__bf16)v;
            }
        }
    }
}

// ---------------------------------------------------------------- attention
// grid: (qtile 0..3, head 0..7, batch 0..31); 256 threads = 4 waves x 32 Q-rows.
__global__ __launch_bounds__(256, 2)
void attn_fwd(const __bf16* __restrict__ qkv, const int* __restrict__ mask,
              __bf16* __restrict__ out)
{
    __shared__ __bf16 lQ[128 * 64];
    __shared__ __bf16 lK[128 * 64];
    __shared__ __bf16 lVt[64 * 128];
    __shared__ float lMask[128];
    __shared__ __bf16 lP[4][32 * 32];

    const int b = blockIdx.z, h = blockIdx.y, q0 = blockIdx.x * 128;
    const int t = threadIdx.x, w = t >> 6, lane = t & 63;
    const int l16 = lane & 15, lk = lane >> 4;

    const __bf16* qbase = qkv + (size_t)b * 512 * 1536 + h * 64;
    const __bf16* kbase = qbase + 512;
    const __bf16* vbase = qbase + 1024;

    #pragma unroll
    for (int r = 0; r < 4; ++r) {
        int c = t + r * 256;
        int row = c >> 3, ch = c & 7;
        *reinterpret_cast<int4v*>(&lQ[row * 64 + ((ch ^ (row & 7)) * 8)]) =
            *reinterpret_cast<const int4v*>(qbase + (size_t)(q0 + row) * 1536 + ch * 8);
    }

    float m_run[2][4], l_run[2][4];
    f32x4 oacc[2][4] = {};
    #pragma unroll
    for (int mi = 0; mi < 2; ++mi)
        #pragma unroll
        for (int j = 0; j < 4; ++j) { m_run[mi][j] = -1e30f; l_run[mi][j] = 0.f; }

    for (int kt = 0; kt < 512; kt += 128) {
        __syncthreads();
        #pragma unroll
        for (int r = 0; r < 4; ++r) {
            int c = t + r * 256;
            int row = c >> 3, ch = c & 7;
            *reinterpret_cast<int4v*>(&lK[row * 64 + ((ch ^ (row & 7)) * 8)]) =
                *reinterpret_cast<const int4v*>(kbase + (size_t)(kt + row) * 1536 + ch * 8);
        }
        #pragma unroll
        for (int r = 0; r < 4; ++r) {
            int c = t + r * 256;
            int d = c & 63, kc8 = c >> 6;
            bf16x8 vv;
            #pragma unroll
            for (int i = 0; i < 8; ++i)
                vv[i] = vbase[(size_t)(kt + kc8 * 8 + i) * 1536 + d];
            *reinterpret_cast<bf16x8*>(&lVt[d * 128 + ((kc8 ^ (d & 7)) * 8)]) = vv;
        }
        if (t < 128) lMask[t] = (mask[b * 512 + kt + t] == 0) ? -1e9f : 0.f;
        __syncthreads();

        // scores: wave w handles Q rows [w*32, w*32+32) of the 128-row tile
        f32x4 sacc[2][8] = {};
        #pragma unroll
        for (int kc = 0; kc < 2; ++kc) {
            bf16x8 qf[2], kf[8];
            #pragma unroll
            for (int mi = 0; mi < 2; ++mi) {
                int row = w * 32 + mi * 16 + l16;
                qf[mi] = *reinterpret_cast<const bf16x8*>(&lQ[row * 64 + (((kc * 4 + lk) ^ (row & 7)) * 8)]);
            }
            #pragma unroll
            for (int ni = 0; ni < 8; ++ni) {
                int row = ni * 16 + l16;
                kf[ni] = *reinterpret_cast<const bf16x8*>(&lK[row * 64 + (((kc * 4 + lk) ^ (row & 7)) * 8)]);
            }
            #pragma unroll
            for (int mi = 0; mi < 2; ++mi)
                #pragma unroll
                for (int ni = 0; ni < 8; ++ni)
                    sacc[mi][ni] = __builtin_amdgcn_mfma_f32_16x16x32_bf16(qf[mi], kf[ni], sacc[mi][ni], 0, 0, 0);
        }

        // online softmax (rows: (lane>>4)*4+j per mi; cols: ni*16 + (lane&15))
        #pragma unroll
        for (int mi = 0; mi < 2; ++mi) {
            float alpha[4];
            #pragma unroll
            for (int j = 0; j < 4; ++j) {
                float mx = -1e30f;
                #pragma unroll
                for (int ni = 0; ni < 8; ++ni) {
                    float sv = sacc[mi][ni][j] * 0.125f + lMask[ni * 16 + l16];
                    sacc[mi][ni][j] = sv;
                    mx = fmaxf(mx, sv);
                }
                #pragma unroll
                for (int d = 8; d >= 1; d >>= 1) mx = fmaxf(mx, __shfl_xor(mx, d));
                float mn = fmaxf(m_run[mi][j], mx);
                alpha[j] = exp2f((m_run[mi][j] - mn) * LOG2E);
                m_run[mi][j] = mn;
                float ps = 0.f;
                #pragma unroll
                for (int ni = 0; ni < 8; ++ni) {
                    float p = exp2f((sacc[mi][ni][j] - mn) * LOG2E);
                    sacc[mi][ni][j] = p;
                    ps += p;
                }
                l_run[mi][j] = l_run[mi][j] * alpha[j] + ps;
            }
            #pragma unroll
            for (int dn = 0; dn < 4; ++dn)
                #pragma unroll
                for (int j = 0; j < 4; ++j)
                    oacc[mi][dn][j] *= alpha[j];
        }

        // PV: per 32-wide K chunk, round-trip P through per-wave LDS
        __bf16* lp = &lP[w][0];
        #pragma unroll
        for (int kc = 0; kc < 4; ++kc) {
            #pragma unroll
            for (int mi = 0; mi < 2; ++mi)
                #pragma unroll
                for (int n2 = 0; n2 < 2; ++n2)
                    #pragma unroll
                    for (int j = 0; j < 4; ++j) {
                        int row = mi * 16 + lk * 4 + j;
                        lp[row * 32 + n2 * 16 + l16] = (__bf16)sacc[mi][kc * 2 + n2][j];
                    }
            bf16x8 pf[2], vf[4];
            #pragma unroll
            for (int mi = 0; mi < 2; ++mi)
                pf[mi] = *reinterpret_cast<const bf16x8*>(&lp[(mi * 16 + l16) * 32 + lk * 8]);
            #pragma unroll
            for (int dn = 0; dn < 4; ++dn) {
                int d = dn * 16 + l16;
                vf[dn] = *reinterpret_cast<const bf16x8*>(&lVt[d * 128 + (((kc * 4 + lk) ^ (d & 7)) * 8)]);
            }
            #pragma unroll
            for (int mi = 0; mi < 2; ++mi)
                #pragma unroll
                for (int dn = 0; dn < 4; ++dn)
                    oacc[mi][dn] = __builtin_amdgcn_mfma_f32_16x16x32_bf16(pf[mi], vf[dn], oacc[mi][dn], 0, 0, 0);
        }
    }

    #pragma unroll
    for (int mi = 0; mi < 2; ++mi) {
        float linv[4];
        #pragma unroll
        for (int j = 0; j < 4; ++j) {
            float s = l_run[mi][j];
            #pragma unroll
            for (int d = 8; d >= 1; d >>= 1) s += __shfl_xor(s, d);
            linv[j] = 1.f / s;
        }
        #pragma unroll
        for (int dn = 0; dn < 4; ++dn)
            #pragma unroll
            for (int j = 0; j < 4; ++j) {
                int row = q0 + w * 32 + mi * 16 + lk * 4 + j;
                int col = h * 64 + dn * 16 + l16;
                out[(size_t)(b * 512 + row) * 512 + col] = (__bf16)(oacc[mi][dn][j] * linv[j]);
            }
    }
}

// ---------------------------------------------------------------- elementwise

__device__ __forceinline__ float wsum64(float v)
{
    #pragma unroll
    for (int d = 32; d >= 1; d >>= 1) v += __shfl_xor(v, d);
    return v;
}

// x = LN(resid + proj) * gamma + beta; writes f32 master + bf16 copy. Wave per token.
__global__ __launch_bounds__(256)
void ln_fuse(const float* resid, const float* __restrict__ proj,
             const float* __restrict__ gamma, const float* __restrict__ beta,
             float* xfo, __bf16* __restrict__ xbo)
{
    int tok = blockIdx.x * 4 + (threadIdx.x >> 6);
    int lane = threadIdx.x & 63;
    size_t base = (size_t)tok * 512 + lane * 8;
    float y[8];
    {
        f32x4 a0 = *reinterpret_cast<const f32x4*>(resid + base);
        f32x4 a1 = *reinterpret_cast<const f32x4*>(resid + base + 4);
        f32x4 p0 = *reinterpret_cast<const f32x4*>(proj + base);
        f32x4 p1 = *reinterpret_cast<const f32x4*>(proj + base + 4);
        #pragma unroll
        for (int i = 0; i < 4; ++i) { y[i] = a0[i] + p0[i]; y[4 + i] = a1[i] + p1[i]; }
    }
    float s = 0.f;
    #pragma unroll
    for (int i = 0; i < 8; ++i) s += y[i];
    float mean = wsum64(s) * (1.f / 512.f);
    float v = 0.f;
    #pragma unroll
    for (int i = 0; i < 8; ++i) { float d = y[i] - mean; v += d * d; }
    float rstd = rsqrtf(wsum64(v) * (1.f / 512.f) + 1e-5f);
    int hh = lane * 8;
    f32x4 g0 = *reinterpret_cast<const f32x4*>(gamma + hh);
    f32x4 g1 = *reinterpret_cast<const f32x4*>(gamma + hh + 4);
    f32x4 b0 = *reinterpret_cast<const f32x4*>(beta + hh);
    f32x4 b1 = *reinterpret_cast<const f32x4*>(beta + hh + 4);
    f32x4 o0, o1;
    bf16x8 ob;
    #pragma unroll
    for (int i = 0; i < 4; ++i) {
        float t0 = (y[i] - mean) * rstd * g0[i] + b0[i];
        float t1 = (y[4 + i] - mean) * rstd * g1[i] + b1[i];
        o0[i] = t0; o1[i] = t1;
        ob[i] = (__bf16)t0; ob[4 + i] = (__bf16)t1;
    }
    *reinterpret_cast<f32x4*>(xfo + base) = o0;
    *reinterpret_cast<f32x4*>(xfo + base + 4) = o1;
    *reinterpret_cast<bf16x8*>(xbo + base) = ob;
}

// x = relu(LN(se)*g+b) + act_emb[g,a] + rtg*retW + retb + time_emb[t] + game_emb[g]
__global__ __launch_bounds__(256)
void embed_fin(const float* __restrict__ seraw, const int* __restrict__ gi,
               const int* __restrict__ actions, const float* __restrict__ rtg,
               const int* __restrict__ ts,
               const float* __restrict__ olg, const float* __restrict__ olb,
               const float* __restrict__ act_emb, const float* __restrict__ retW,
               const float* __restrict__ retb, const float* __restrict__ time_emb,
               const float* __restrict__ game_emb,
               float* __restrict__ xfo, __bf16* __restrict__ xbo)
{
    int tok = blockIdx.x * 4 + (threadIdx.x >> 6);
    int lane = threadIdx.x & 63;
    int b = tok >> 9;
    int g = gi[b];
    int a = actions[tok];
    int tt = ts[tok];
    float rv = rtg[tok];
    size_t base = (size_t)tok * 512 + lane * 8;
    int hh = lane * 8;

    float y[8];
    {
        f32x4 a0 = *reinterpret_cast<const f32x4*>(seraw + base);
        f32x4 a1 = *reinterpret_cast<const f32x4*>(seraw + base + 4);
        #pragma unroll
        for (int i = 0; i < 4; ++i) { y[i] = a0[i]; y[4 + i] = a1[i]; }
    }
    float s = 0.f;
    #pragma unroll
    for (int i = 0; i < 8; ++i) s += y[i];
    float mean = wsum64(s) * (1.f / 512.f);
    float v = 0.f;
    #pragma unroll
    for (int i = 0; i < 8; ++i) { float d = y[i] - mean; v += d * d; }
    float rstd = rsqrtf(wsum64(v) * (1.f / 512.f) + 1e-5f);

    const float* gp = olg + (size_t)g * 512 + hh;
    const float* bp = olb + (size_t)g * 512 + hh;
    const float* ap = act_emb + ((size_t)g * 18 + a) * 512 + hh;
    const float* tp = time_emb + (size_t)tt * 512 + hh;
    const float* ep = game_emb + (size_t)g * 512 + hh;
    const float* rwp = retW + hh;
    const float* rbp = retb + hh;

    f32x4 o0, o1;
    bf16x8 ob;
    #pragma unroll
    for (int half = 0; half < 2; ++half) {
        f32x4 gv = *reinterpret_cast<const f32x4*>(gp + half * 4);
        f32x4 bv = *reinterpret_cast<const f32x4*>(bp + half * 4);
        f32x4 av = *reinterpret_cast<const f32x4*>(ap + half * 4);
        f32x4 tv = *reinterpret_cast<const f32x4*>(tp + half * 4);
        f32x4 ev = *reinterpret_cast<const f32x4*>(ep + half * 4);
        f32x4 rw = *reinterpret_cast<const f32x4*>(rwp + half * 4);
        f32x4 rb = *reinterpret_cast<const f32x4*>(rbp + half * 4);
        #pragma unroll
        for (int i = 0; i < 4; ++i) {
            float n = (y[half * 4 + i] - mean) * rstd * gv[i] + bv[i];
            n = fmaxf(n, 0.f);
            float o = n + av[i] + rv * rw[i] + rb[i] + tv[i] + ev[i];
            if (half == 0) o0[i] = o; else o1[i] = o;
            ob[half * 4 + i] = (__bf16)o;
        }
    }
    *reinterpret_cast<f32x4*>(xfo + base) = o0;
    *reinterpret_cast<f32x4*>(xfo + base + 4) = o1;
    *reinterpret_cast<bf16x8*>(xbo + base) = ob;
}

// action (18) + return (1) heads; wave per token, shuffle-reduce dots.
__global__ __launch_bounds__(256)
void head_ar(const float* __restrict__ xf, const int* __restrict__ gi,
             const float* __restrict__ ahWt, const float* __restrict__ ah_b,
             const float* __restrict__ rhW, const float* __restrict__ rhb,
             float* __restrict__ outA, float* __restrict__ outR)
{
    int tok = blockIdx.x * 4 + (threadIdx.x >> 6);
    int lane = threadIdx.x & 63;
    int b = tok >> 9;
    int g = gi[b];
    size_t base = (size_t)tok * 512 + lane * 8;
    float x[8];
    {
        f32x4 a0 = *reinterpret_cast<const f32x4*>(xf + base);
        f32x4 a1 = *reinterpret_cast<const f32x4*>(xf + base + 4);
        #pragma unroll
        for (int i = 0; i < 4; ++i) { x[i] = a0[i]; x[4 + i] = a1[i]; }
    }
    #pragma unroll 1
    for (int a = 0; a < 18; ++a) {
        const float* wp = ahWt + ((size_t)g * 18 + a) * 512 + lane * 8;
        f32x4 w0 = *reinterpret_cast<const f32x4*>(wp);
        f32x4 w1 = *reinterpret_cast<const f32x4*>(wp + 4);
        float p = 0.f;
        #pragma unroll
        for (int i = 0; i < 4; ++i) { p += x[i] * w0[i]; p += x[4 + i] * w1[i]; }
        p = wsum64(p);
        if (lane == 0) outA[(size_t)tok * 18 + a] = p + ah_b[g * 18 + a];
    }
    {
        const float* wp = rhW + lane * 8;
        f32x4 w0 = *reinterpret_cast<const f32x4*>(wp);
        f32x4 w1 = *reinterpret_cast<const f32x4*>(wp + 4);
        float p = 0.f;
        #pragma unroll
        for (int i = 0; i < 4; ++i) { p += x[i] * w0[i]; p += x[4 + i] * w1[i]; }
        p = wsum64(p);
        if (lane == 0) outR[tok] = p + rhb[0];
    }
}

// ---------------------------------------------------------------- launch

extern "C" void kernel_launch(void* const* d_in, const int* in_sizes, int n_in,
                              void* d_out, int out_size, void* d_ws, size_t ws_size,
                              hipStream_t stream)
{
    (void)in_sizes; (void)n_in; (void)out_size; (void)ws_size;

    const int*   gi       = (const int*)d_in[0];
    const float* states   = (const float*)d_in[1];
    const int*   actions  = (const int*)d_in[2];
    const float* rtg      = (const float*)d_in[3];
    const int*   ts       = (const int*)d_in[4];
    const int*   amask    = (const int*)d_in[5];
    const float* game_emb = (const float*)d_in[6];
    const float* obs_W    = (const float*)d_in[7];
    const float* obs_b    = (const float*)d_in[8];
    const float* obs_ln_g = (const float*)d_in[9];
    const float* obs_ln_b = (const float*)d_in[10];
    const float* act_emb  = (const float*)d_in[11];
    const float* ret_W    = (const float*)d_in[12];
    const float* ret_b    = (const float*)d_in[13];
    const float* time_emb = (const float*)d_in[14];
    const float* Wqkv     = (const float*)d_in[15];
    const float* bqkv     = (const float*)d_in[16];
    const float* Wo       = (const float*)d_in[17];
    const float* bo       = (const float*)d_in[18];
    const float* ln1_g    = (const float*)d_in[19];
    const float* ln1_b    = (const float*)d_in[20];
    const float* W1       = (const float*)d_in[21];
    const float* b1       = (const float*)d_in[22];
    const float* W2       = (const float*)d_in[23];
    const float* b2       = (const float*)d_in[24];
    const float* ln2_g    = (const float*)d_in[25];
    const float* ln2_b    = (const float*)d_in[26];
    const float* sh_W     = (const float*)d_in[27];
    const float* sh_b     = (const float*)d_in[28];
    const float* ah_W     = (const float*)d_in[29];
    const float* ah_b     = (const float*)d_in[30];
    const float* rh_W     = (const float*)d_in[31];
    const float* rh_b     = (const float*)d_in[32];

    char* wsb = (char*)d_ws;
    // layout (bytes), total ~198 MiB:
    float*  xf      = (float*)(wsb + 0);                       // 32 MiB
    __bf16* xb      = (__bf16*)(wsb + 33554432);               // 16 MiB
    float*  tmp     = (float*)(wsb + 50331648);                // 32 MiB
    __bf16* qkvB    = (__bf16*)(wsb + 83886080);               // region R1 (64 MiB): qkv / ff1 / states
    __bf16* ff1B    = qkvB;
    __bf16* statesB = qkvB;                                    // dead before qkv written
    __bf16* obswB   = (__bf16*)(wsb + 83886080 + 8388608);     // inside R1, dead before qkv
    __bf16* attnB   = (__bf16*)(wsb + 150994944);              // 16 MiB
    __bf16* wqkvB   = (__bf16*)(wsb + 167772160);
    __bf16* woB     = (__bf16*)(wsb + 177209344);
    __bf16* w1B     = (__bf16*)(wsb + 180355072);
    __bf16* w2B     = (__bf16*)(wsb + 192937984);
    __bf16* shwB    = (__bf16*)(wsb + 205520896);
    float*  ahwT    = (float*)(wsb + 207618048);

    // weight conversions (each call; deterministic)
    cvt_f32_bf16<<<4608, 256, 0, stream>>>(Wqkv, wqkvB, 1179648);
    cvt_f32_bf16<<<1536, 256, 0, stream>>>(Wo, woB, 393216);
    cvt_f32_bf16<<<6144, 256, 0, stream>>>(W1, w1B, 1572864);
    cvt_f32_bf16<<<6144, 256, 0, stream>>>(W2, w2B, 1572864);
    cvt_f32_bf16<<<4096, 256, 0, stream>>>(states, statesB, 1048576);
    transpose_cvt<<<dim3(512, 8), 256, 0, stream>>>(obs_W, obswB, 256, 512);
    transpose_cvt<<<dim3(512, 8), 256, 0, stream>>>(sh_W, shwB, 512, 256);
    transpose_f32<<<dim3(36, 8), 256, 0, stream>>>(ah_W, ahwT, 512, 18);

    // embedding: se_raw = states @ obs_W[g] + obs_b[g]  (grouped, z=batch)
    gemm_bt<<<dim3(4, 4, 32), 256, 0, stream>>>(
        statesB, (size_t)512 * 256, obswB, (size_t)512 * 256, obs_b, 512,
        tmp, nullptr, (size_t)512 * 512, gi, 256, 512, 0);
    embed_fin<<<4096, 256, 0, stream>>>(tmp, gi, actions, rtg, ts,
        obs_ln_g, obs_ln_b, act_emb, ret_W, ret_b, time_emb, game_emb, xf, xb);

    for (int l = 0; l < 6; ++l) {
        // QKV
        gemm_bt<<<dim3(12, 128, 1), 256, 0, stream>>>(
            xb, 0, wqkvB + (size_t)l * 1536 * 512, 0, bqkv + l * 1536, 0,
            nullptr, qkvB, 0, nullptr, 512, 1536, 0);
        // attention
        attn_fwd<<<dim3(4, 8, 32), 256, 0, stream>>>(qkvB, amask, attnB);
        // Wo projection
        gemm_bt<<<dim3(4, 128, 1), 256, 0, stream>>>(
            attnB, 0, woB + (size_t)l * 512 * 512, 0, bo + l * 512, 0,
            tmp, nullptr, 0, nullptr, 512, 512, 0);
        ln_fuse<<<4096, 256, 0, stream>>>(xf, tmp, ln1_g + l * 512, ln1_b + l * 512, xf, xb);
        // FF1 (relu, bf16 out)
        gemm_bt<<<dim3(16, 128, 1), 256, 0, stream>>>(
            xb, 0, w1B + (size_t)l * 2048 * 512, 0, b1 + l * 2048, 0,
            nullptr, ff1B, 0, nullptr, 512, 2048, 1);
        // FF2
        gemm_bt<<<dim3(4, 128, 1), 256, 0, stream>>>(
            ff1B, 0, w2B + (size_t)l * 512 * 2048, 0, b2 + l * 512, 0,
            tmp, nullptr, 0, nullptr, 2048, 512, 0);
        ln_fuse<<<4096, 256, 0, stream>>>(xf, tmp, ln2_g + l * 512, ln2_b + l * 512, xf, xb);
    }

    // state head (grouped, writes d_out[0 : 32*512*256))
    gemm_bt<<<dim3(2, 4, 32), 256, 0, stream>>>(
        xb, (size_t)512 * 512, shwB, (size_t)256 * 512, sh_b, 256,
        (float*)d_out, nullptr, (size_t)512 * 256, gi, 512, 256, 0);
    // action + return heads
    head_ar<<<4096, 256, 0, stream>>>(xf, gi, ahwT, ah_b, rh_W, rh_b,
        (float*)d_out + 4194304, (float*)d_out + 4489216);
}

// Round 2
// 1634.592 us; speedup vs baseline: 1.1253x; 1.1253x over previous
//
#include <hip/hip_runtime.h>

typedef __bf16 bf16x4 __attribute__((ext_vector_type(4)));
typedef __bf16 bf16x8 __attribute__((ext_vector_type(8)));
typedef float f32x4 __attribute__((ext_vector_type(4)));
typedef int int4v __attribute__((ext_vector_type(4)));

#define LOG2E 1.44269504088896340736f

typedef const __attribute__((address_space(1))) void gvoid_t;
typedef __attribute__((address_space(3))) void lvoid_t;

// ---------------------------------------------------------------- converts

__global__ void cvt_f32_bf16(const float* __restrict__ src, __bf16* __restrict__ dst, int n4)
{
    int i = blockIdx.x * blockDim.x + threadIdx.x;
    if (i >= n4) return;
    f32x4 v = *reinterpret_cast<const f32x4*>(src + (size_t)i * 4);
    bf16x4 o;
    #pragma unroll
    for (int k = 0; k < 4; ++k) o[k] = (__bf16)v[k];
    *reinterpret_cast<bf16x4*>(dst + (size_t)i * 4) = o;
}

// src (nmat, R, C) -> dst (nmat, C, R), bf16
__global__ void transpose_cvt(const float* __restrict__ src, __bf16* __restrict__ dst, int R, int C)
{
    int m = blockIdx.y;
    int n = R * C;
    int i = blockIdx.x * 256 + threadIdx.x;
    if (i >= n) return;
    int c = i / R, r = i - c * R;
    dst[(size_t)m * n + i] = (__bf16)src[(size_t)m * n + (size_t)r * C + c];
}

// src (nmat, R, C) -> dst (nmat, C, R), f32
__global__ void transpose_f32(const float* __restrict__ src, float* __restrict__ dst, int R, int C)
{
    int m = blockIdx.y;
    int n = R * C;
    int i = blockIdx.x * 256 + threadIdx.x;
    if (i >= n) return;
    int c = i / R, r = i - c * R;
    dst[(size_t)m * n + i] = src[(size_t)m * n + (size_t)r * C + c];
}

// ---------------------------------------------------------------- GEMM
// C[z][m][n] = sum_k A[z][m][k] * B[g][n][k] + bias[g][n]   (B^T layout)
// A: (M,K) row-major bf16; B: (N,K) row-major bf16; out f32 (Cf) or bf16 (Cb).
// 128x128 tile, 4 waves, BK=32, global_load_lds staging (linear LDS dest,
// chunk-XOR pre-swizzled global source), LDS-staged coalesced epilogue,
// bijective XCD swizzle on (x,y).
__global__ __launch_bounds__(256, 2)
void gemm_bt(const __bf16* __restrict__ A, size_t strideA,
             const __bf16* __restrict__ B, size_t strideB,
             const float* __restrict__ bias, int strideBias,
             float* Cf, __bf16* Cb, size_t strideC,
             const int* __restrict__ gidx,
             int K, int ldc, int relu)
{
    __shared__ __align__(16) char smem[16384];
    __bf16* lA  = (__bf16*)smem;
    __bf16* lB  = (__bf16*)(smem + 8192);
    __bf16* lCb = (__bf16*)smem;
    float*  lCf = (float*)smem;

    const int z = blockIdx.z;
    const int g = gidx ? gidx[z] : 0;
    const __bf16* Ab = A + (size_t)z * strideA;
    const __bf16* Bb = B + (size_t)g * strideB;

    // XCD-aware swizzle: consecutive same-XCD dispatches get consecutive tiles
    const int nx = gridDim.x;
    const int nwg = nx * gridDim.y;
    int orig = blockIdx.y * nx + blockIdx.x;
    int wg = ((nwg & 7) == 0) ? ((orig & 7) * (nwg >> 3) + (orig >> 3)) : orig;
    const int bm = (wg / nx) * 128, bn = (wg % nx) * 128;

    const int t = threadIdx.x;
    const int w = t >> 6, lane = t & 63;
    const int wr = (w >> 1) * 64, wc = (w & 1) * 64;
    const int l16 = lane & 15, lk = lane >> 4;

    // staging: lane -> (row srow, 16B chunk), source chunk XOR-swizzled by row&3
    const int srow = lane >> 2;
    const int schunk = (lane & 3) ^ (srow & 3);
    // fragment-read chunk (inverse of source swizzle)
    const int ca = (lk ^ (l16 & 3)) * 8;

    f32x4 acc[4][4] = {};

    for (int kt = 0; kt < K; kt += 32) {
        __syncthreads();
        #pragma unroll
        for (int jj = 0; jj < 2; ++jj) {
            const __bf16* ga = Ab + (size_t)(bm + w * 32 + jj * 16 + srow) * K + kt + schunk * 8;
            __builtin_amdgcn_global_load_lds((gvoid_t*)ga, (lvoid_t*)&lA[(w * 32 + jj * 16) * 32], 16, 0, 0);
            const __bf16* gb = Bb + (size_t)(bn + w * 32 + jj * 16 + srow) * K + kt + schunk * 8;
            __builtin_amdgcn_global_load_lds((gvoid_t*)gb, (lvoid_t*)&lB[(w * 32 + jj * 16) * 32], 16, 0, 0);
        }
        __syncthreads();

        bf16x8 af[4], bfr[4];
        #pragma unroll
        for (int i = 0; i < 4; ++i) {
            af[i]  = *reinterpret_cast<const bf16x8*>(&lA[(wr + i * 16 + l16) * 32 + ca]);
            bfr[i] = *reinterpret_cast<const bf16x8*>(&lB[(wc + i * 16 + l16) * 32 + ca]);
        }
        #pragma unroll
        for (int mi = 0; mi < 4; ++mi)
            #pragma unroll
            for (int ni = 0; ni < 4; ++ni)
                acc[mi][ni] = __builtin_amdgcn_mfma_f32_16x16x32_bf16(af[mi], bfr[ni], acc[mi][ni], 0, 0, 0);
    }

    const float* biasb = bias ? bias + (size_t)g * strideBias : nullptr;

    if (Cb) {
        // bf16 out: 2 passes of 64 rows staged in LDS, coalesced 256B-row stores
        #pragma unroll
        for (int p = 0; p < 2; ++p) {
            __syncthreads();
            if (wr == p * 64) {
                #pragma unroll
                for (int ni = 0; ni < 4; ++ni) {
                    int col = wc + ni * 16 + l16;
                    float bv = biasb ? biasb[bn + col] : 0.f;
                    #pragma unroll
                    for (int mi = 0; mi < 4; ++mi)
                        #pragma unroll
                        for (int j = 0; j < 4; ++j) {
                            float v = acc[mi][ni][j] + bv;
                            if (relu) v = fmaxf(v, 0.f);
                            lCb[(mi * 16 + lk * 4 + j) * 128 + col] = (__bf16)v;
                        }
                }
            }
            __syncthreads();
            #pragma unroll
            for (int it = 0; it < 4; ++it) {
                int off = it * 2048 + t * 8;
                int rl = off >> 7, col = off & 127;
                *reinterpret_cast<int4v*>(Cb + (size_t)z * strideC + (size_t)(bm + p * 64 + rl) * ldc + bn + col) =
                    *reinterpret_cast<const int4v*>(&lCb[off]);
            }
        }
    } else {
        // f32 out: 4 passes of 32 rows
        #pragma unroll
        for (int p = 0; p < 4; ++p) {
            __syncthreads();
            #pragma unroll
            for (int mi = 0; mi < 4; ++mi) {
                int rl = wr + mi * 16;
                if (rl >= p * 32 && rl < p * 32 + 32) {
                    #pragma unroll
                    for (int ni = 0; ni < 4; ++ni) {
                        int col = wc + ni * 16 + l16;
                        float bv = biasb ? biasb[bn + col] : 0.f;
                        #pragma unroll
                        for (int j = 0; j < 4; ++j) {
                            float v = acc[mi][ni][j] + bv;
                            if (relu) v = fmaxf(v, 0.f);
                            lCf[(rl - p * 32 + lk * 4 + j) * 128 + col] = v;
                        }
                    }
                }
            }
            __syncthreads();
            #pragma unroll
            for (int it = 0; it < 4; ++it) {
                int off = it * 1024 + t * 4;
                int rl = off >> 7, col = off & 127;
                *reinterpret_cast<f32x4*>(Cf + (size_t)z * strideC + (size_t)(bm + p * 32 + rl) * ldc + bn + col) =
                    *reinterpret_cast<const f32x4*>(&lCf[off]);
            }
        }
    }
}

// ---------------------------------------------------------------- attention
// grid: (qtile 0..3, head 0..7, batch 0..31); 256 threads = 4 waves x 32 Q-rows.
__global__ __launch_bounds__(256, 2)
void attn_fwd(const __bf16* __restrict__ qkv, const int* __restrict__ mask,
              __bf16* __restrict__ out)
{
    __shared__ __bf16 lQ[128 * 64];
    __shared__ __bf16 lK[128 * 64];
    __shared__ __bf16 lVt[64 * 128];
    __shared__ float lMask[128];
    __shared__ __bf16 lP[4][32 * 32];

    const int b = blockIdx.z, h = blockIdx.y, q0 = blockIdx.x * 128;
    const int t = threadIdx.x, w = t >> 6, lane = t & 63;
    const int l16 = lane & 15, lk = lane >> 4;

    const __bf16* qbase = qkv + (size_t)b * 512 * 1536 + h * 64;
    const __bf16* kbase = qbase + 512;
    const __bf16* vbase = qbase + 1024;

    #pragma unroll
    for (int r = 0; r < 4; ++r) {
        int c = t + r * 256;
        int row = c >> 3, ch = c & 7;
        *reinterpret_cast<int4v*>(&lQ[row * 64 + ((ch ^ (row & 7)) * 8)]) =
            *reinterpret_cast<const int4v*>(qbase + (size_t)(q0 + row) * 1536 + ch * 8);
    }

    float m_run[2][4], l_run[2][4];
    f32x4 oacc[2][4] = {};
    #pragma unroll
    for (int mi = 0; mi < 2; ++mi)
        #pragma unroll
        for (int j = 0; j < 4; ++j) { m_run[mi][j] = -1e30f; l_run[mi][j] = 0.f; }

    for (int kt = 0; kt < 512; kt += 128) {
        __syncthreads();
        #pragma unroll
        for (int r = 0; r < 4; ++r) {
            int c = t + r * 256;
            int row = c >> 3, ch = c & 7;
            *reinterpret_cast<int4v*>(&lK[row * 64 + ((ch ^ (row & 7)) * 8)]) =
                *reinterpret_cast<const int4v*>(kbase + (size_t)(kt + row) * 1536 + ch * 8);
        }
        #pragma unroll
        for (int r = 0; r < 4; ++r) {
            int c = t + r * 256;
            int d = c & 63, kc8 = c >> 6;
            bf16x8 vv;
            #pragma unroll
            for (int i = 0; i < 8; ++i)
                vv[i] = vbase[(size_t)(kt + kc8 * 8 + i) * 1536 + d];
            *reinterpret_cast<bf16x8*>(&lVt[d * 128 + ((kc8 ^ (d & 7)) * 8)]) = vv;
        }
        if (t < 128) lMask[t] = (mask[b * 512 + kt + t] == 0) ? -1e9f : 0.f;
        __syncthreads();

        // scores: wave w handles Q rows [w*32, w*32+32) of the 128-row tile
        f32x4 sacc[2][8] = {};
        #pragma unroll
        for (int kc = 0; kc < 2; ++kc) {
            bf16x8 qf[2], kf[8];
            #pragma unroll
            for (int mi = 0; mi < 2; ++mi) {
                int row = w * 32 + mi * 16 + l16;
                qf[mi] = *reinterpret_cast<const bf16x8*>(&lQ[row * 64 + (((kc * 4 + lk) ^ (row & 7)) * 8)]);
            }
            #pragma unroll
            for (int ni = 0; ni < 8; ++ni) {
                int row = ni * 16 + l16;
                kf[ni] = *reinterpret_cast<const bf16x8*>(&lK[row * 64 + (((kc * 4 + lk) ^ (row & 7)) * 8)]);
            }
            #pragma unroll
            for (int mi = 0; mi < 2; ++mi)
                #pragma unroll
                for (int ni = 0; ni < 8; ++ni)
                    sacc[mi][ni] = __builtin_amdgcn_mfma_f32_16x16x32_bf16(qf[mi], kf[ni], sacc[mi][ni], 0, 0, 0);
        }

        // online softmax (rows: (lane>>4)*4+j per mi; cols: ni*16 + (lane&15))
        #pragma unroll
        for (int mi = 0; mi < 2; ++mi) {
            float alpha[4];
            #pragma unroll
            for (int j = 0; j < 4; ++j) {
                float mx = -1e30f;
                #pragma unroll
                for (int ni = 0; ni < 8; ++ni) {
                    float sv = sacc[mi][ni][j] * 0.125f + lMask[ni * 16 + l16];
                    sacc[mi][ni][j] = sv;
                    mx = fmaxf(mx, sv);
                }
                #pragma unroll
                for (int d = 8; d >= 1; d >>= 1) mx = fmaxf(mx, __shfl_xor(mx, d));
                float mn = fmaxf(m_run[mi][j], mx);
                alpha[j] = exp2f((m_run[mi][j] - mn) * LOG2E);
                m_run[mi][j] = mn;
                float ps = 0.f;
                #pragma unroll
                for (int ni = 0; ni < 8; ++ni) {
                    float p = exp2f((sacc[mi][ni][j] - mn) * LOG2E);
                    sacc[mi][ni][j] = p;
                    ps += p;
                }
                l_run[mi][j] = l_run[mi][j] * alpha[j] + ps;
            }
            #pragma unroll
            for (int dn = 0; dn < 4; ++dn)
                #pragma unroll
                for (int j = 0; j < 4; ++j)
                    oacc[mi][dn][j] *= alpha[j];
        }

        // PV: per 32-wide K chunk, round-trip P through per-wave LDS
        __bf16* lp = &lP[w][0];
        #pragma unroll
        for (int kc = 0; kc < 4; ++kc) {
            #pragma unroll
            for (int mi = 0; mi < 2; ++mi)
                #pragma unroll
                for (int n2 = 0; n2 < 2; ++n2)
                    #pragma unroll
                    for (int j = 0; j < 4; ++j) {
                        int row = mi * 16 + lk * 4 + j;
                        lp[row * 32 + n2 * 16 + l16] = (__bf16)sacc[mi][kc * 2 + n2][j];
                    }
            bf16x8 pf[2], vf[4];
            #pragma unroll
            for (int mi = 0; mi < 2; ++mi)
                pf[mi] = *reinterpret_cast<const bf16x8*>(&lp[(mi * 16 + l16) * 32 + lk * 8]);
            #pragma unroll
            for (int dn = 0; dn < 4; ++dn) {
                int d = dn * 16 + l16;
                vf[dn] = *reinterpret_cast<const bf16x8*>(&lVt[d * 128 + (((kc * 4 + lk) ^ (d & 7)) * 8)]);
            }
            #pragma unroll
            for (int mi = 0; mi < 2; ++mi)
                #pragma unroll
                for (int dn = 0; dn < 4; ++dn)
                    oacc[mi][dn] = __builtin_amdgcn_mfma_f32_16x16x32_bf16(pf[mi], vf[dn], oacc[mi][dn], 0, 0, 0);
        }
    }

    #pragma unroll
    for (int mi = 0; mi < 2; ++mi) {
        float linv[4];
        #pragma unroll
        for (int j = 0; j < 4; ++j) {
            float s = l_run[mi][j];
            #pragma unroll
            for (int d = 8; d >= 1; d >>= 1) s += __shfl_xor(s, d);
            linv[j] = 1.f / s;
        }
        #pragma unroll
        for (int dn = 0; dn < 4; ++dn)
            #pragma unroll
            for (int j = 0; j < 4; ++j) {
                int row = q0 + w * 32 + mi * 16 + lk * 4 + j;
                int col = h * 64 + dn * 16 + l16;
                out[(size_t)(b * 512 + row) * 512 + col] = (__bf16)(oacc[mi][dn][j] * linv[j]);
            }
    }
}

// ---------------------------------------------------------------- elementwise

__device__ __forceinline__ float wsum64(float v)
{
    #pragma unroll
    for (int d = 32; d >= 1; d >>= 1) v += __shfl_xor(v, d);
    return v;
}

// x = LN(resid + proj) * gamma + beta; writes f32 master + bf16 copy. Wave per token.
__global__ __launch_bounds__(256)
void ln_fuse(const float* resid, const __bf16* __restrict__ proj,
             const float* __restrict__ gamma, const float* __restrict__ beta,
             float* xfo, __bf16* __restrict__ xbo)
{
    int tok = blockIdx.x * 4 + (threadIdx.x >> 6);
    int lane = threadIdx.x & 63;
    size_t base = (size_t)tok * 512 + lane * 8;
    float y[8];
    {
        f32x4 a0 = *reinterpret_cast<const f32x4*>(resid + base);
        f32x4 a1 = *reinterpret_cast<const f32x4*>(resid + base + 4);
        bf16x8 pv = *reinterpret_cast<const bf16x8*>(proj + base);
        #pragma unroll
        for (int i = 0; i < 4; ++i) { y[i] = a0[i] + (float)pv[i]; y[4 + i] = a1[i] + (float)pv[4 + i]; }
    }
    float s = 0.f;
    #pragma unroll
    for (int i = 0; i < 8; ++i) s += y[i];
    float mean = wsum64(s) * (1.f / 512.f);
    float v = 0.f;
    #pragma unroll
    for (int i = 0; i < 8; ++i) { float d = y[i] - mean; v += d * d; }
    float rstd = rsqrtf(wsum64(v) * (1.f / 512.f) + 1e-5f);
    int hh = lane * 8;
    f32x4 g0 = *reinterpret_cast<const f32x4*>(gamma + hh);
    f32x4 g1 = *reinterpret_cast<const f32x4*>(gamma + hh + 4);
    f32x4 b0 = *reinterpret_cast<const f32x4*>(beta + hh);
    f32x4 b1 = *reinterpret_cast<const f32x4*>(beta + hh + 4);
    f32x4 o0, o1;
    bf16x8 ob;
    #pragma unroll
    for (int i = 0; i < 4; ++i) {
        float t0 = (y[i] - mean) * rstd * g0[i] + b0[i];
        float t1 = (y[4 + i] - mean) * rstd * g1[i] + b1[i];
        o0[i] = t0; o1[i] = t1;
        ob[i] = (__bf16)t0; ob[4 + i] = (__bf16)t1;
    }
    *reinterpret_cast<f32x4*>(xfo + base) = o0;
    *reinterpret_cast<f32x4*>(xfo + base + 4) = o1;
    *reinterpret_cast<bf16x8*>(xbo + base) = ob;
}

// x = relu(LN(se)*g+b) + act_emb[g,a] + rtg*retW + retb + time_emb[t] + game_emb[g]
__global__ __launch_bounds__(256)
void embed_fin(const __bf16* __restrict__ seraw, const int* __restrict__ gi,
               const int* __restrict__ actions, const float* __restrict__ rtg,
               const int* __restrict__ ts,
               const float* __restrict__ olg, const float* __restrict__ olb,
               const float* __restrict__ act_emb, const float* __restrict__ retW,
               const float* __restrict__ retb, const float* __restrict__ time_emb,
               const float* __restrict__ game_emb,
               float* __restrict__ xfo, __bf16* __restrict__ xbo)
{
    int tok = blockIdx.x * 4 + (threadIdx.x >> 6);
    int lane = threadIdx.x & 63;
    int b = tok >> 9;
    int g = gi[b];
    int a = actions[tok];
    int tt = ts[tok];
    float rv = rtg[tok];
    size_t base = (size_t)tok * 512 + lane * 8;
    int hh = lane * 8;

    float y[8];
    {
        bf16x8 a0 = *reinterpret_cast<const bf16x8*>(seraw + base);
        #pragma unroll
        for (int i = 0; i < 8; ++i) y[i] = (float)a0[i];
    }
    float s = 0.f;
    #pragma unroll
    for (int i = 0; i < 8; ++i) s += y[i];
    float mean = wsum64(s) * (1.f / 512.f);
    float v = 0.f;
    #pragma unroll
    for (int i = 0; i < 8; ++i) { float d = y[i] - mean; v += d * d; }
    float rstd = rsqrtf(wsum64(v) * (1.f / 512.f) + 1e-5f);

    const float* gp = olg + (size_t)g * 512 + hh;
    const float* bp = olb + (size_t)g * 512 + hh;
    const float* ap = act_emb + ((size_t)g * 18 + a) * 512 + hh;
    const float* tp = time_emb + (size_t)tt * 512 + hh;
    const float* ep = game_emb + (size_t)g * 512 + hh;
    const float* rwp = retW + hh;
    const float* rbp = retb + hh;

    f32x4 o0, o1;
    bf16x8 ob;
    #pragma unroll
    for (int half = 0; half < 2; ++half) {
        f32x4 gv = *reinterpret_cast<const f32x4*>(gp + half * 4);
        f32x4 bv = *reinterpret_cast<const f32x4*>(bp + half * 4);
        f32x4 av = *reinterpret_cast<const f32x4*>(ap + half * 4);
        f32x4 tv = *reinterpret_cast<const f32x4*>(tp + half * 4);
        f32x4 ev = *reinterpret_cast<const f32x4*>(ep + half * 4);
        f32x4 rw = *reinterpret_cast<const f32x4*>(rwp + half * 4);
        f32x4 rb = *reinterpret_cast<const f32x4*>(rbp + half * 4);
        #pragma unroll
        for (int i = 0; i < 4; ++i) {
            float n = (y[half * 4 + i] - mean) * rstd * gv[i] + bv[i];
            n = fmaxf(n, 0.f);
            float o = n + av[i] + rv * rw[i] + rb[i] + tv[i] + ev[i];
            if (half == 0) o0[i] = o; else o1[i] = o;
            ob[half * 4 + i] = (__bf16)o;
        }
    }
    *reinterpret_cast<f32x4*>(xfo + base) = o0;
    *reinterpret_cast<f32x4*>(xfo + base + 4) = o1;
    *reinterpret_cast<bf16x8*>(xbo + base) = ob;
}

// action (18) + return (1) heads; wave per token, shuffle-reduce dots.
__global__ __launch_bounds__(256)
void head_ar(const float* __restrict__ xf, const int* __restrict__ gi,
             const float* __restrict__ ahWt, const float* __restrict__ ah_b,
             const float* __restrict__ rhW, const float* __restrict__ rhb,
             float* __restrict__ outA, float* __restrict__ outR)
{
    int tok = blockIdx.x * 4 + (threadIdx.x >> 6);
    int lane = threadIdx.x & 63;
    int b = tok >> 9;
    int g = gi[b];
    size_t base = (size_t)tok * 512 + lane * 8;
    float x[8];
    {
        f32x4 a0 = *reinterpret_cast<const f32x4*>(xf + base);
        f32x4 a1 = *reinterpret_cast<const f32x4*>(xf + base + 4);
        #pragma unroll
        for (int i = 0; i < 4; ++i) { x[i] = a0[i]; x[4 + i] = a1[i]; }
    }
    #pragma unroll 1
    for (int a = 0; a < 18; ++a) {
        const float* wp = ahWt + ((size_t)g * 18 + a) * 512 + lane * 8;
        f32x4 w0 = *reinterpret_cast<const f32x4*>(wp);
        f32x4 w1 = *reinterpret_cast<const f32x4*>(wp + 4);
        float p = 0.f;
        #pragma unroll
        for (int i = 0; i < 4; ++i) { p += x[i] * w0[i]; p += x[4 + i] * w1[i]; }
        p = wsum64(p);
        if (lane == 0) outA[(size_t)tok * 18 + a] = p + ah_b[g * 18 + a];
    }
    {
        const float* wp = rhW + lane * 8;
        f32x4 w0 = *reinterpret_cast<const f32x4*>(wp);
        f32x4 w1 = *reinterpret_cast<const f32x4*>(wp + 4);
        float p = 0.f;
        #pragma unroll
        for (int i = 0; i < 4; ++i) { p += x[i] * w0[i]; p += x[4 + i] * w1[i]; }
        p = wsum64(p);
        if (lane == 0) outR[tok] = p + rhb[0];
    }
}

// ---------------------------------------------------------------- launch

extern "C" void kernel_launch(void* const* d_in, const int* in_sizes, int n_in,
                              void* d_out, int out_size, void* d_ws, size_t ws_size,
                              hipStream_t stream)
{
    (void)in_sizes; (void)n_in; (void)out_size; (void)ws_size;

    const int*   gi       = (const int*)d_in[0];
    const float* states   = (const float*)d_in[1];
    const int*   actions  = (const int*)d_in[2];
    const float* rtg      = (const float*)d_in[3];
    const int*   ts       = (const int*)d_in[4];
    const int*   amask    = (const int*)d_in[5];
    const float* game_emb = (const float*)d_in[6];
    const float* obs_W    = (const float*)d_in[7];
    const float* obs_b    = (const float*)d_in[8];
    const float* obs_ln_g = (const float*)d_in[9];
    const float* obs_ln_b = (const float*)d_in[10];
    const float* act_emb  = (const float*)d_in[11];
    const float* ret_W    = (const float*)d_in[12];
    const float* ret_b    = (const float*)d_in[13];
    const float* time_emb = (const float*)d_in[14];
    const float* Wqkv     = (const float*)d_in[15];
    const float* bqkv     = (const float*)d_in[16];
    const float* Wo       = (const float*)d_in[17];
    const float* bo       = (const float*)d_in[18];
    const float* ln1_g    = (const float*)d_in[19];
    const float* ln1_b    = (const float*)d_in[20];
    const float* W1       = (const float*)d_in[21];
    const float* b1       = (const float*)d_in[22];
    const float* W2       = (const float*)d_in[23];
    const float* b2       = (const float*)d_in[24];
    const float* ln2_g    = (const float*)d_in[25];
    const float* ln2_b    = (const float*)d_in[26];
    const float* sh_W     = (const float*)d_in[27];
    const float* sh_b     = (const float*)d_in[28];
    const float* ah_W     = (const float*)d_in[29];
    const float* ah_b     = (const float*)d_in[30];
    const float* rh_W     = (const float*)d_in[31];
    const float* rh_b     = (const float*)d_in[32];

    char* wsb = (char*)d_ws;
    float*  xf      = (float*)(wsb + 0);                       // 32 MiB
    __bf16* xb      = (__bf16*)(wsb + 33554432);               // 16 MiB
    __bf16* tmp     = (__bf16*)(wsb + 50331648);               // 16 MiB (bf16 now)
    __bf16* qkvB    = (__bf16*)(wsb + 83886080);               // region R1 (64 MiB): qkv / ff1 / states
    __bf16* ff1B    = qkvB;
    __bf16* statesB = qkvB;                                    // dead before qkv written
    __bf16* obswB   = (__bf16*)(wsb + 83886080 + 8388608);     // inside R1, dead before qkv
    __bf16* attnB   = (__bf16*)(wsb + 150994944);              // 16 MiB
    __bf16* wqkvB   = (__bf16*)(wsb + 167772160);
    __bf16* woB     = (__bf16*)(wsb + 177209344);
    __bf16* w1B     = (__bf16*)(wsb + 180355072);
    __bf16* w2B     = (__bf16*)(wsb + 192937984);
    __bf16* shwB    = (__bf16*)(wsb + 205520896);
    float*  ahwT    = (float*)(wsb + 207618048);

    // weight conversions (each call; deterministic)
    cvt_f32_bf16<<<4608, 256, 0, stream>>>(Wqkv, wqkvB, 1179648);
    cvt_f32_bf16<<<1536, 256, 0, stream>>>(Wo, woB, 393216);
    cvt_f32_bf16<<<6144, 256, 0, stream>>>(W1, w1B, 1572864);
    cvt_f32_bf16<<<6144, 256, 0, stream>>>(W2, w2B, 1572864);
    cvt_f32_bf16<<<4096, 256, 0, stream>>>(states, statesB, 1048576);
    transpose_cvt<<<dim3(512, 8), 256, 0, stream>>>(obs_W, obswB, 256, 512);
    transpose_cvt<<<dim3(512, 8), 256, 0, stream>>>(sh_W, shwB, 512, 256);
    transpose_f32<<<dim3(36, 8), 256, 0, stream>>>(ah_W, ahwT, 512, 18);

    // embedding: se_raw = states @ obs_W[g] + obs_b[g]  (grouped, z=batch)
    gemm_bt<<<dim3(4, 4, 32), 256, 0, stream>>>(
        statesB, (size_t)512 * 256, obswB, (size_t)512 * 256, obs_b, 512,
        nullptr, tmp, (size_t)512 * 512, gi, 256, 512, 0);
    embed_fin<<<4096, 256, 0, stream>>>(tmp, gi, actions, rtg, ts,
        obs_ln_g, obs_ln_b, act_emb, ret_W, ret_b, time_emb, game_emb, xf, xb);

    for (int l = 0; l < 6; ++l) {
        // QKV
        gemm_bt<<<dim3(12, 128, 1), 256, 0, stream>>>(
            xb, 0, wqkvB + (size_t)l * 1536 * 512, 0, bqkv + l * 1536, 0,
            nullptr, qkvB, 0, nullptr, 512, 1536, 0);
        // attention
        attn_fwd<<<dim3(4, 8, 32), 256, 0, stream>>>(qkvB, amask, attnB);
        // Wo projection
        gemm_bt<<<dim3(4, 128, 1), 256, 0, stream>>>(
            attnB, 0, woB + (size_t)l * 512 * 512, 0, bo + l * 512, 0,
            nullptr, tmp, 0, nullptr, 512, 512, 0);
        ln_fuse<<<4096, 256, 0, stream>>>(xf, tmp, ln1_g + l * 512, ln1_b + l * 512, xf, xb);
        // FF1 (relu, bf16 out)
        gemm_bt<<<dim3(16, 128, 1), 256, 0, stream>>>(
            xb, 0, w1B + (size_t)l * 2048 * 512, 0, b1 + l * 2048, 0,
            nullptr, ff1B, 0, nullptr, 512, 2048, 1);
        // FF2
        gemm_bt<<<dim3(4, 128, 1), 256, 0, stream>>>(
            ff1B, 0, w2B + (size_t)l * 512 * 2048, 0, b2 + l * 512, 0,
            nullptr, tmp, 0, nullptr, 2048, 512, 0);
        ln_fuse<<<4096, 256, 0, stream>>>(xf, tmp, ln2_g + l * 512, ln2_b + l * 512, xf, xb);
    }

    // state head (grouped, writes d_out[0 : 32*512*256))
    gemm_bt<<<dim3(2, 4, 32), 256, 0, stream>>>(
        xb, (size_t)512 * 512, shwB, (size_t)256 * 512, sh_b, 256,
        (float*)d_out, nullptr, (size_t)512 * 256, gi, 512, 256, 0);
    // action + return heads
    head_ar<<<4096, 256, 0, stream>>>(xf, gi, ahwT, ah_b, rh_W, rh_b,
        (float*)d_out + 4194304, (float*)d_out + 4489216);
}